// Round 11
// baseline (402.588 us; speedup 1.0000x reference)
//
#include <hip/hip_runtime.h>
#include <stdint.h>

// ---------------------------------------------------------------------------
// ModifiedSelfAttention (Wan block): QKV GEMM -> RMSNorm+RoPE -> flash attn -> O GEMM
// R12: split-K removed (it was solving a residency problem that no longer
//      exists at 2-blocks/CU; grid 360 is one co-resident round):
//   - attn runs all 59 K-tiles per block, normalizes in-register, writes AO
//     bf16 directly. reduce_kernel / Opart / Ml deleted (-107MB traffic).
//   - qkv GEMM emits bf16 Yq/Yk (same f2bf epilogue as Vb); normrope reads
//     bf16. Halves Y write+read traffic.
//   Attn math/pipeline (R6-verified) otherwise untouched.
// ---------------------------------------------------------------------------

#define DIM   1536
#define S_TOT 3744
#define NHEAD 12
#define HD    128
#define QT2   30          // q-tiles per head (128 q per block)
#define KVT   59          // key tiles of 64 (ceil(3744/64))

using short8 = __attribute__((ext_vector_type(8))) short;   // 8 bf16 (4 VGPRs)
using f32x4  = __attribute__((ext_vector_type(4))) float;   // 16x16 MFMA C/D
using f32x16 = __attribute__((ext_vector_type(16))) float;  // 32x32 MFMA C/D
using f32x2  = __attribute__((ext_vector_type(2))) float;

__device__ __forceinline__ unsigned short f2bf(float f) {
  unsigned u = __builtin_bit_cast(unsigned, f);
  u += 0x7fffu + ((u >> 16) & 1u);     // RNE
  return (unsigned short)(u >> 16);
}

__device__ __forceinline__ float bf2f(unsigned short u) {
  return __builtin_bit_cast(float, (unsigned)u << 16);
}

__device__ __forceinline__ short8 mk8(unsigned a, unsigned b, unsigned c, unsigned d) {
  union { unsigned u[4]; short8 s; } x;
  x.u[0] = a; x.u[1] = b; x.u[2] = c; x.u[3] = d;
  return x.s;
}

// async global->LDS, 16B per lane. LDS dest must be wave-uniform base + lane*16.
__device__ __forceinline__ void gl_lds16(const void* g, void* l) {
  auto gp = (const __attribute__((address_space(1))) unsigned int*)g;
  auto lp = (__attribute__((address_space(3))) unsigned int*)(uintptr_t)l;
  __builtin_amdgcn_global_load_lds(gp, lp, 16, 0, 0);
}

// ---------------------------------------------------------------------------
// fp32 -> bf16 convert, all 5 arrays in one launch
// ---------------------------------------------------------------------------
#define NX4 (S_TOT * DIM / 4)
#define NW4 (DIM * DIM / 4)
__global__ __launch_bounds__(256) void cvt5_kernel(
    const float* __restrict__ x, const float* __restrict__ wq,
    const float* __restrict__ wk, const float* __restrict__ wv,
    const float* __restrict__ wo,
    unsigned short* __restrict__ xb, unsigned short* __restrict__ wqb,
    unsigned short* __restrict__ wkb, unsigned short* __restrict__ wvb,
    unsigned short* __restrict__ wob) {
  int gid = blockIdx.x * 256 + threadIdx.x;
  const float* src; unsigned short* dst; int off;
  if (gid < NX4)                { src = x;  dst = xb;  off = gid; }
  else if (gid < NX4 + NW4)     { src = wq; dst = wqb; off = gid - NX4; }
  else if (gid < NX4 + 2 * NW4) { src = wk; dst = wkb; off = gid - NX4 - NW4; }
  else if (gid < NX4 + 3 * NW4) { src = wv; dst = wvb; off = gid - NX4 - 2 * NW4; }
  else if (gid < NX4 + 4 * NW4) { src = wo; dst = wob; off = gid - NX4 - 3 * NW4; }
  else return;
  float4 v = ((const float4*)src)[off];
  ushort4 o;
  o.x = f2bf(v.x); o.y = f2bf(v.y); o.z = f2bf(v.z); o.w = f2bf(v.w);
  ((ushort4*)dst)[off] = o;
}

// ---------------------------------------------------------------------------
// NT GEMM: C[m,n] = sum_k A[m,k]*W[n,k] + bias[n].
// BK=64 as two proven [128][32] sub-buffers; 32 MFMA per barrier-pair (R10).
// mode 0: f32 out; mode 1: bf16 out.
// ---------------------------------------------------------------------------
__device__ __forceinline__ void gemm_body(const unsigned short* __restrict__ A,
                                          const unsigned short* __restrict__ W,
                                          const float* __restrict__ bias,
                                          float* __restrict__ outF,
                                          unsigned short* __restrict__ outB,
                                          int M, int mode, int m0, int n0) {
  constexpr int K = DIM, N = DIM;
  __shared__ unsigned short As[2][128 * 32];
  __shared__ unsigned short Ws[2][128 * 32];
  int tid = threadIdx.x;
  int w = tid >> 6, lane = tid & 63;
  int wr = w >> 1, wc = w & 1, q4 = lane >> 4, ql = lane & 15;

  f32x4 acc[4][4];
  const f32x4 zero4 = {0.f, 0.f, 0.f, 0.f};
#pragma unroll
  for (int i = 0; i < 4; i++)
#pragma unroll
    for (int j = 0; j < 4; j++) acc[i][j] = zero4;

  for (int k0 = 0; k0 < K; k0 += 64) {
    __syncthreads();
#pragma unroll
    for (int half = 0; half < 2; half++) {
#pragma unroll
      for (int r = 0; r < 2; r++) {
        int idx = r * 256 + tid;
        int row = idx >> 2, ch = idx & 3;
        int am = m0 + row; am = (am < M) ? am : (M - 1);
        gl_lds16(A + (size_t)am * K + k0 + half * 32 + ch * 8, &As[half][idx * 8]);
        gl_lds16(W + (size_t)(n0 + row) * K + k0 + half * 32 + ch * 8, &Ws[half][idx * 8]);
      }
    }
    __syncthreads();
#pragma unroll
    for (int half = 0; half < 2; half++) {
      short8 af[4], wf[4];
#pragma unroll
      for (int i = 0; i < 4; i++)
        af[i] = *(const short8*)&As[half][(wr * 64 + i * 16 + ql) * 32 + q4 * 8];
#pragma unroll
      for (int j = 0; j < 4; j++)
        wf[j] = *(const short8*)&Ws[half][(wc * 64 + j * 16 + ql) * 32 + q4 * 8];
#pragma unroll
      for (int i = 0; i < 4; i++)
#pragma unroll
        for (int j = 0; j < 4; j++)
          acc[i][j] = __builtin_amdgcn_mfma_f32_16x16x32_bf16(af[i], wf[j], acc[i][j], 0, 0, 0);
    }
  }

  float bb[4];
#pragma unroll
  for (int j = 0; j < 4; j++) bb[j] = bias[n0 + wc * 64 + j * 16 + ql];
#pragma unroll
  for (int i = 0; i < 4; i++) {
#pragma unroll
    for (int rg = 0; rg < 4; rg++) {
      int row = m0 + wr * 64 + i * 16 + q4 * 4 + rg;
      if (row < M) {
#pragma unroll
        for (int j = 0; j < 4; j++) {
          int col = n0 + wc * 64 + j * 16 + ql;
          float v = acc[i][j][rg] + bb[j];
          if (mode == 0) outF[(size_t)row * N + col] = v;
          else           outB[(size_t)row * N + col] = f2bf(v);
        }
      }
    }
  }
}

// qkv: flat grid 1080 = 8 XCD chunks of 135 (= one z each, W L2-resident).
// All three outputs now bf16.
__global__ __launch_bounds__(256, 4) void gemm_qkv_kernel(
    const unsigned short* __restrict__ xb,
    const unsigned short* __restrict__ wqb, const unsigned short* __restrict__ wkb,
    const unsigned short* __restrict__ wvb,
    const float* __restrict__ bq, const float* __restrict__ bk, const float* __restrict__ bv,
    unsigned short* __restrict__ Yqb, unsigned short* __restrict__ Ykb,
    unsigned short* __restrict__ Vb) {
  const int NWG = 3 * 30 * 12;             // 1080
  int bid = blockIdx.x;
  int xcd = bid & 7, bix = bid >> 3;
  int wg = xcd * (NWG >> 3) + bix;         // chunks of 135
  int z = wg / 360;
  int r = wg - z * 360;
  int m = r / 12, n = r % 12;
  const unsigned short* W = (z == 0) ? wqb : ((z == 1) ? wkb : wvb);
  const float* bias       = (z == 0) ? bq  : ((z == 1) ? bk  : bv);
  unsigned short* dst     = (z == 0) ? Yqb : ((z == 1) ? Ykb : Vb);
  gemm_body(xb, W, bias, nullptr, dst, S_TOT, 1, m * 128, n * 128);
}

// out: flat grid 360 = 8 XCD chunks of 45.
__global__ __launch_bounds__(256, 4) void gemm_out_kernel(
    const unsigned short* __restrict__ AO, const unsigned short* __restrict__ wob,
    const float* __restrict__ bo, float* __restrict__ out) {
  const int NWG = 30 * 12;                 // 360
  int bid = blockIdx.x;
  int xcd = bid & 7, bix = bid >> 3;
  int wg = xcd * (NWG >> 3) + bix;         // chunks of 45
  int m = wg / 12, n = wg % 12;
  gemm_body(AO, wob, bo, out, nullptr, S_TOT, 0, m * 128, n * 128);
}

// ---------------------------------------------------------------------------
// RMSNorm + RoPE, bf16 input (Yqb/Ykb). Q pre-scaled by sm_scale*log2(e).
// ---------------------------------------------------------------------------
__global__ __launch_bounds__(256) void normrope_kernel(
    const unsigned short* __restrict__ Yqb, const unsigned short* __restrict__ Ykb,
    const float* __restrict__ gq, const float* __restrict__ gk,
    const float* __restrict__ freqs,
    unsigned short* __restrict__ Qb, unsigned short* __restrict__ Kb) {
  int s = blockIdx.x;
  int tid = threadIdx.x;
  int w = tid >> 6, lane = tid & 63;
  const ushort2* yq2 = (const ushort2*)(Yqb + (size_t)s * DIM);
  const ushort2* yk2 = (const ushort2*)(Ykb + (size_t)s * DIM);
  f32x2 vq[3], vk[3];
  float ssq = 0.f, ssk = 0.f;
#pragma unroll
  for (int r = 0; r < 3; r++) {
    int p = tid + 256 * r;
    ushort2 uq = yq2[p], uk = yk2[p];
    vq[r].x = bf2f(uq.x); vq[r].y = bf2f(uq.y);
    vk[r].x = bf2f(uk.x); vk[r].y = bf2f(uk.y);
    ssq += vq[r].x * vq[r].x + vq[r].y * vq[r].y;
    ssk += vk[r].x * vk[r].x + vk[r].y * vk[r].y;
  }
#pragma unroll
  for (int d = 1; d < 64; d <<= 1) {
    ssq += __shfl_xor(ssq, d);
    ssk += __shfl_xor(ssk, d);
  }
  __shared__ float rq[4], rk[4];
  if (lane == 0) { rq[w] = ssq; rk[w] = ssk; }
  __syncthreads();
  float tq = rq[0] + rq[1] + rq[2] + rq[3];
  float tk = rk[0] + rk[1] + rk[2] + rk[3];
  const float SM_L2 = 0.08838834764831845f * 1.4426950408889634f; // scale*log2e
  float invq = rsqrtf(tq * (1.f / DIM) + 1e-6f) * SM_L2;
  float invk = rsqrtf(tk * (1.f / DIM) + 1e-6f);

  int fi = s / (26 * 48);
  int hi = (s / 48) % 26;
  int wi = s % 48;
#pragma unroll
  for (int r = 0; r < 3; r++) {
    int p = tid + 256 * r;
    int c = p & 63;
    int frow = (c < 22) ? fi : ((c < 43) ? hi : wi);
    float ang = freqs[frow * 64 + c];
    float sn, cs;
    __sincosf(ang, &sn, &cs);
    {
      float a = vq[r].x * invq * gq[2 * p];
      float b = vq[r].y * invq * gq[2 * p + 1];
      ushort2 o; o.x = f2bf(a * cs - b * sn); o.y = f2bf(a * sn + b * cs);
      ((ushort2*)Qb)[(size_t)s * (DIM / 2) + p] = o;
    }
    {
      float a = vk[r].x * invk * gk[2 * p];
      float b = vk[r].y * invk * gk[2 * p + 1];
      ushort2 o; o.x = f2bf(a * cs - b * sn); o.y = f2bf(a * sn + b * cs);
      ((ushort2*)Kb)[(size_t)s * (DIM / 2) + p] = o;
    }
  }
}

// ---------------------------------------------------------------------------
// V transpose (unchanged, proven)
// ---------------------------------------------------------------------------
__global__ __launch_bounds__(256) void vtrans_kernel(const unsigned short* __restrict__ Vb,
                                                     unsigned short* __restrict__ Vt) {
  int d0 = blockIdx.x * 64, s0 = blockIdx.y * 64;
  __shared__ unsigned short t[64][65];
  int tid = threadIdx.x;
#pragma unroll
  for (int r = 0; r < 4; r++) {
    int idx = r * 256 + tid;
    int sr = idx >> 4, c4 = (idx & 15) * 4;
    ushort4 v; v.x = v.y = v.z = v.w = 0;
    int s = s0 + sr;
    if (s < S_TOT) v = *(const ushort4*)(Vb + (size_t)s * DIM + d0 + c4);
    t[sr][c4 + 0] = v.x; t[sr][c4 + 1] = v.y; t[sr][c4 + 2] = v.z; t[sr][c4 + 3] = v.w;
  }
  __syncthreads();
#pragma unroll
  for (int r = 0; r < 4; r++) {
    int idx = r * 256 + tid;
    int dr = idx >> 4, s4 = (idx & 15) * 4;
    if (s0 + s4 < S_TOT) {
      ushort4 v;
      v.x = t[s4 + 0][dr]; v.y = t[s4 + 1][dr]; v.z = t[s4 + 2][dr]; v.w = t[s4 + 3][dr];
      *(ushort4*)(Vt + (size_t)(d0 + dr) * S_TOT + s0 + s4) = v;
    }
  }
}

// ---------------------------------------------------------------------------
// Flash attention (R6 math/pipeline, KSPLIT removed): 32x32x16 MFMA,
// in-register P, 4 waves x 32q = 128q/block, double-buffered K/V (KVBLK=64)
// with counted vmcnt(8). Grid 360 = one co-resident round (2 blocks/CU cap).
// Each block runs all 59 key tiles, normalizes in-register, writes AO bf16.
// ---------------------------------------------------------------------------
__global__ __launch_bounds__(256, 2) void attn_kernel(
    const unsigned short* __restrict__ Qb, const unsigned short* __restrict__ Kb,
    const unsigned short* __restrict__ Vt, unsigned short* __restrict__ AO,
    const int* __restrict__ seq_lens) {
  // bijective XCD-chunked remap: 360 % 8 == 0 -> chunks of 45 (~1.5 heads'
  // K/V = 2.9MB per XCD L2).
  const int NWG = QT2 * NHEAD;             // 360
  int bid = blockIdx.x;
  int xcd = bid & 7, bix = bid >> 3;
  int wg = xcd * (NWG >> 3) + bix;         // chunks of 45
  int qt = wg % QT2;
  int h  = wg / QT2;

  int tid = threadIdx.x;                   // 0..255
  int wv = tid >> 6, lane = tid & 63;
  int lo = lane & 31, hf = lane >> 5;
  int seqlen = seq_lens[0]; if (seqlen > S_TOT) seqlen = S_TOT;

  __shared__ unsigned short Kl[2][64 * 128];  // 2 x 16 KB, chunk-swizzled
  __shared__ unsigned short Vl[2][128 * 64];  // 2 x 16 KB, chunk-swizzled

  int q0 = qt * 128 + wv * 32;
  bool wact = (q0 < S_TOT);
  const size_t hoff = (size_t)h * HD;

  auto stage = [&](int buf, int t) {
    int k0 = t * 64;
    const unsigned short* kseg = Kb + (size_t)k0 * DIM + hoff;
#pragma unroll
    for (int r = 0; r < 4; r++) {
      int idx = r * 256 + tid;
      int row = idx >> 4, c = idx & 15;
      int g = c ^ (row & 15);
      gl_lds16(kseg + (size_t)row * DIM + g * 8, &Kl[buf][idx * 8]);
    }
    int kmax = S_TOT - 8 - k0;             // clamp key-chunk start (last tile)
#pragma unroll
    for (int r = 0; r < 4; r++) {
      int idx = r * 256 + tid;
      int row = idx >> 3, c = idx & 7;
      int g = c ^ (row & 7);
      int kc = g * 8; if (kc > kmax) kc = kmax;
      gl_lds16(Vt + (hoff + row) * S_TOT + k0 + kc, &Vl[buf][idx * 8]);
    }
  };

  // Q B-frags (hoisted): qf[ks] = Q[q0+lo][ks*16 + hf*8 .. +7]
  short8 qf[8];
  {
    int qrow = q0 + lo; if (qrow > S_TOT - 1) qrow = S_TOT - 1;
#pragma unroll
    for (int ks = 0; ks < 8; ks++)
      qf[ks] = *(const short8*)(Qb + (size_t)qrow * DIM + hoff + ks * 16 + hf * 8);
  }
  asm volatile("s_waitcnt vmcnt(0)" ::: "memory");  // Q landed; vmcnt clean

  f32x16 o[4];
#pragma unroll
  for (int dq = 0; dq < 4; dq++)
#pragma unroll
    for (int r = 0; r < 16; r++) o[dq][r] = 0.f;
  float m_run = -3.0e38f, l_run = 0.f;

  stage(0, 0);                             // prologue: first tile in flight

  for (int t = 0; t < KVT; ++t) {
    int cur = t & 1;
    int k0 = t * 64;
    __builtin_amdgcn_s_barrier();          // all reads of buf[cur^1] done
    asm volatile("" ::: "memory");
    if (t + 1 < KVT) {
      stage(cur ^ 1, t + 1);               // prefetch next tile (8 gl_lds/thr)
      asm volatile("s_waitcnt vmcnt(8)" ::: "memory");   // tile t landed (mine)
    } else {
      asm volatile("s_waitcnt vmcnt(0)" ::: "memory");
    }
    __builtin_amdgcn_sched_barrier(0);
    __builtin_amdgcn_s_barrier();          // tile t landed (everyone)
    asm volatile("" ::: "memory");
    if (!wact) continue;

    // ---- QK^T: two 32-key halves, dual accumulation chains ----
    f32x16 s0, s1;
#pragma unroll
    for (int r = 0; r < 16; r++) { s0[r] = 0.f; s1[r] = 0.f; }
    __builtin_amdgcn_s_setprio(1);
#pragma unroll
    for (int ks = 0; ks < 8; ks++) {
      int sl = ((ks * 2 + hf) ^ (lo & 15)) * 8;
      short8 kf0 = *(const short8*)&Kl[cur][lo * 128 + sl];
      short8 kf1 = *(const short8*)&Kl[cur][(32 + lo) * 128 + sl];
      s0 = __builtin_amdgcn_mfma_f32_32x32x16_bf16(kf0, qf[ks], s0, 0, 0, 0);
      s1 = __builtin_amdgcn_mfma_f32_32x32x16_bf16(kf1, qf[ks], s1, 0, 0, 0);
    }
    __builtin_amdgcn_s_setprio(0);

    // ---- mask (ragged last tile only) ----
    if (k0 + 64 > seqlen) {
#pragma unroll
      for (int r = 0; r < 16; r++) {
        int key0 = k0 + (r & 3) + 8 * (r >> 2) + 4 * hf;
        if (key0      >= seqlen) s0[r] = -3.0e38f;
        if (key0 + 32 >= seqlen) s1[r] = -3.0e38f;
      }
    }

    // ---- online softmax (exp2 domain; Q pre-scaled) ----
    float mloc = s0[0];
#pragma unroll
    for (int r = 1; r < 16; r++) mloc = fmaxf(mloc, s0[r]);
#pragma unroll
    for (int r = 0; r < 16; r++) mloc = fmaxf(mloc, s1[r]);
    mloc = fmaxf(mloc, __shfl_xor(mloc, 32));

    // defer-max (T13): rescale only when growth > 8 (rare); alpha needs a
    // lane->reg-row redistribution (q=lane&31 -> q=(r&3)+8*(r>>2)+4*hf)
    if (!__all(mloc <= m_run + 8.0f)) {
      float mnew = fmaxf(m_run, mloc);
      float alpha = exp2f(m_run - mnew);   // 0 on first tile
      m_run = mnew;
      l_run *= alpha;
      int lb = lane & 32;
      float ar[16];
#pragma unroll
      for (int r = 0; r < 16; r++)
        ar[r] = __shfl(alpha, ((r & 3) + 8 * (r >> 2) + 4 * hf) | lb);
#pragma unroll
      for (int dq = 0; dq < 4; dq++)
#pragma unroll
        for (int r = 0; r < 16; r++) o[dq][r] *= ar[r];
    }

    // ---- P = exp2(s - m) -> bf16 A-frags fully in-register (T12) ----
    float lloc = 0.f;
    short8 pa[4];
    {
      float p[16];
#pragma unroll
      for (int r = 0; r < 16; r++) { p[r] = exp2f(s0[r] - m_run); lloc += p[r]; }
      unsigned pr[8];
#pragma unroll
      for (int i = 0; i < 8; i++)
        asm("v_cvt_pk_bf16_f32 %0, %1, %2" : "=v"(pr[i]) : "v"(p[2 * i]), "v"(p[2 * i + 1]));
      asm volatile("v_permlane32_swap_b32 %0, %1" : "+v"(pr[0]), "+v"(pr[2]));
      asm volatile("v_permlane32_swap_b32 %0, %1" : "+v"(pr[1]), "+v"(pr[3]));
      asm volatile("v_permlane32_swap_b32 %0, %1" : "+v"(pr[4]), "+v"(pr[6]));
      asm volatile("v_permlane32_swap_b32 %0, %1" : "+v"(pr[5]), "+v"(pr[7]));
      pa[0] = mk8(pr[0], pr[1], pr[2], pr[3]);
      pa[1] = mk8(pr[4], pr[5], pr[6], pr[7]);
    }
    {
      float p[16];
#pragma unroll
      for (int r = 0; r < 16; r++) { p[r] = exp2f(s1[r] - m_run); lloc += p[r]; }
      unsigned pr[8];
#pragma unroll
      for (int i = 0; i < 8; i++)
        asm("v_cvt_pk_bf16_f32 %0, %1, %2" : "=v"(pr[i]) : "v"(p[2 * i]), "v"(p[2 * i + 1]));
      asm volatile("v_permlane32_swap_b32 %0, %1" : "+v"(pr[0]), "+v"(pr[2]));
      asm volatile("v_permlane32_swap_b32 %0, %1" : "+v"(pr[1]), "+v"(pr[3]));
      asm volatile("v_permlane32_swap_b32 %0, %1" : "+v"(pr[4]), "+v"(pr[6]));
      asm volatile("v_permlane32_swap_b32 %0, %1" : "+v"(pr[5]), "+v"(pr[7]));
      pa[2] = mk8(pr[0], pr[1], pr[2], pr[3]);
      pa[3] = mk8(pr[4], pr[5], pr[6], pr[7]);
    }
    lloc += __shfl_xor(lloc, 32);
    l_run += lloc;

    // ---- PV: O[q][d] += P.V, 4 independent acc chains ----
    __builtin_amdgcn_s_setprio(1);
#pragma unroll
    for (int kh2 = 0; kh2 < 4; kh2++) {
      int sl = ((kh2 * 2 + hf) ^ (lo & 7)) * 8;
#pragma unroll
      for (int dq = 0; dq < 4; dq++) {
        short8 vb = *(const short8*)&Vl[cur][(dq * 32 + lo) * 64 + sl];
        o[dq] = __builtin_amdgcn_mfma_f32_32x32x16_bf16(pa[kh2], vb, o[dq], 0, 0, 0);
      }
    }
    __builtin_amdgcn_s_setprio(0);
  }

  if (wact) {
    // normalize in-register and write AO bf16 directly (no partials)
    float il = 1.0f / l_run;               // per-lane, q = lane&31
    int lb = lane & 32;
    float ilr[16];
#pragma unroll
    for (int r = 0; r < 16; r++)
      ilr[r] = __shfl(il, ((r & 3) + 8 * (r >> 2) + 4 * hf) | lb);
#pragma unroll
    for (int dq = 0; dq < 4; dq++)
#pragma unroll
      for (int r = 0; r < 16; r++) {
        int row = q0 + (r & 3) + 8 * (r >> 2) + 4 * hf;
        AO[(size_t)row * DIM + hoff + dq * 32 + lo] = f2bf(o[dq][r] * ilr[r]);
      }
  }
}

// ---------------------------------------------------------------------------
extern "C" void kernel_launch(void* const* d_in, const int* in_sizes, int n_in,
                              void* d_out, int out_size, void* d_ws, size_t ws_size,
                              hipStream_t stream) {
  const float* x    = (const float*)d_in[0];
  const float* wq   = (const float*)d_in[1];
  const float* bq   = (const float*)d_in[2];
  const float* wk   = (const float*)d_in[3];
  const float* bk   = (const float*)d_in[4];
  const float* wv   = (const float*)d_in[5];
  const float* bv   = (const float*)d_in[6];
  const float* wo   = (const float*)d_in[7];
  const float* bo   = (const float*)d_in[8];
  const float* gq   = (const float*)d_in[9];
  const float* gk   = (const float*)d_in[10];
  const float* freqs = (const float*)d_in[11];
  const int*   seq  = (const int*)d_in[12];

  char* ws = (char*)d_ws;
  const size_t SZ_X = (size_t)S_TOT * DIM * 2;   // bf16 [S,DIM]
  const size_t SZ_W = (size_t)DIM * DIM * 2;     // bf16 [DIM,DIM]

  size_t off = 0;
  unsigned short* xb  = (unsigned short*)(ws + off); off += SZ_X;
  unsigned short* wob = (unsigned short*)(ws + off); off += SZ_W;
  unsigned short* Yqb = (unsigned short*)(ws + off); off += SZ_X;
  unsigned short* Ykb = (unsigned short*)(ws + off); off += SZ_X;
  unsigned short* wqb = (unsigned short*)(ws + off); off += SZ_W;
  unsigned short* wkb = (unsigned short*)(ws + off); off += SZ_W;
  unsigned short* wvb = (unsigned short*)(ws + off); off += SZ_W;
  unsigned short* Vb  = (unsigned short*)(ws + off); off += SZ_X;
  unsigned short* Qb  = (unsigned short*)(ws + off); off += SZ_X;
  unsigned short* Kb  = (unsigned short*)(ws + off); off += SZ_X;
  unsigned short* Vt  = (unsigned short*)(ws + off); off += SZ_X;
  unsigned short* AO  = (unsigned short*)(ws + off); off += SZ_X;

  int total4 = NX4 + 4 * NW4;
  cvt5_kernel<<<dim3((total4 + 255) / 256), 256, 0, stream>>>(
      x, wq, wk, wv, wo, xb, wqb, wkb, wvb, wob);

  gemm_qkv_kernel<<<dim3(3 * 30 * 12), 256, 0, stream>>>(
      xb, wqb, wkb, wvb, bq, bk, bv, Yqb, Ykb, Vb);

  normrope_kernel<<<dim3(S_TOT), 256, 0, stream>>>(Yqb, Ykb, gq, gk, freqs, Qb, Kb);

  vtrans_kernel<<<dim3(DIM / 64, (S_TOT + 63) / 64), 256, 0, stream>>>(Vb, Vt);

  attn_kernel<<<dim3(QT2 * NHEAD), 256, 0, stream>>>(Qb, Kb, Vt, AO, seq);

  gemm_out_kernel<<<dim3(30 * 12), 256, 0, stream>>>(AO, wob, bo, (float*)d_out);
}

// Round 12
// 390.520 us; speedup vs baseline: 1.0309x; 1.0309x over previous
//
#include <hip/hip_runtime.h>
#include <stdint.h>

// ---------------------------------------------------------------------------
// ModifiedSelfAttention (Wan block): QKV GEMM -> RMSNorm+RoPE -> flash attn -> O GEMM
// R13: recombine verified halves after R12's lesson (split-K is what keeps
//      grid = 2 full residency rounds at the 2-blocks/CU LDS cap):
//   - attn: KSPLIT=2, grid 720 (R11-verified 151.7us, FETCH 23MB) verbatim
//   - qkv emits bf16 Yq/Yk, normrope reads bf16 (R12's orthogonal win kept)
//   - reduce vectorized: float4 partial reads + ushort4 AO write (~21->13us)
//   - workspace overlay re-derived: xb..wvb (48.66MB dead after normrope)
//     contiguous at base -> Opart 47.19MB + Ml 0.74MB fit exactly.
// ---------------------------------------------------------------------------

#define DIM   1536
#define S_TOT 3744
#define NHEAD 12
#define HD    128
#define QT2   30          // q-tiles per head (128 q per block)
#define KVT   59          // key tiles of 64 (ceil(3744/64))
#define KSPLIT 2          // split-K factor (tiles [0,30) / [30,59))

using short8 = __attribute__((ext_vector_type(8))) short;   // 8 bf16 (4 VGPRs)
using f32x4  = __attribute__((ext_vector_type(4))) float;   // 16x16 MFMA C/D
using f32x16 = __attribute__((ext_vector_type(16))) float;  // 32x32 MFMA C/D
using f32x2  = __attribute__((ext_vector_type(2))) float;

__device__ __forceinline__ unsigned short f2bf(float f) {
  unsigned u = __builtin_bit_cast(unsigned, f);
  u += 0x7fffu + ((u >> 16) & 1u);     // RNE
  return (unsigned short)(u >> 16);
}

__device__ __forceinline__ float bf2f(unsigned short u) {
  return __builtin_bit_cast(float, (unsigned)u << 16);
}

__device__ __forceinline__ short8 mk8(unsigned a, unsigned b, unsigned c, unsigned d) {
  union { unsigned u[4]; short8 s; } x;
  x.u[0] = a; x.u[1] = b; x.u[2] = c; x.u[3] = d;
  return x.s;
}

// async global->LDS, 16B per lane. LDS dest must be wave-uniform base + lane*16.
__device__ __forceinline__ void gl_lds16(const void* g, void* l) {
  auto gp = (const __attribute__((address_space(1))) unsigned int*)g;
  auto lp = (__attribute__((address_space(3))) unsigned int*)(uintptr_t)l;
  __builtin_amdgcn_global_load_lds(gp, lp, 16, 0, 0);
}

// ---------------------------------------------------------------------------
// fp32 -> bf16 convert, all 5 arrays in one launch
// ---------------------------------------------------------------------------
#define NX4 (S_TOT * DIM / 4)
#define NW4 (DIM * DIM / 4)
__global__ __launch_bounds__(256) void cvt5_kernel(
    const float* __restrict__ x, const float* __restrict__ wq,
    const float* __restrict__ wk, const float* __restrict__ wv,
    const float* __restrict__ wo,
    unsigned short* __restrict__ xb, unsigned short* __restrict__ wqb,
    unsigned short* __restrict__ wkb, unsigned short* __restrict__ wvb,
    unsigned short* __restrict__ wob) {
  int gid = blockIdx.x * 256 + threadIdx.x;
  const float* src; unsigned short* dst; int off;
  if (gid < NX4)                { src = x;  dst = xb;  off = gid; }
  else if (gid < NX4 + NW4)     { src = wq; dst = wqb; off = gid - NX4; }
  else if (gid < NX4 + 2 * NW4) { src = wk; dst = wkb; off = gid - NX4 - NW4; }
  else if (gid < NX4 + 3 * NW4) { src = wv; dst = wvb; off = gid - NX4 - 2 * NW4; }
  else if (gid < NX4 + 4 * NW4) { src = wo; dst = wob; off = gid - NX4 - 3 * NW4; }
  else return;
  float4 v = ((const float4*)src)[off];
  ushort4 o;
  o.x = f2bf(v.x); o.y = f2bf(v.y); o.z = f2bf(v.z); o.w = f2bf(v.w);
  ((ushort4*)dst)[off] = o;
}

// ---------------------------------------------------------------------------
// NT GEMM: C[m,n] = sum_k A[m,k]*W[n,k] + bias[n].
// BK=64 as two proven [128][32] sub-buffers; 32 MFMA per barrier-pair (R10).
// mode 0: f32 out; mode 1: bf16 out.
// ---------------------------------------------------------------------------
__device__ __forceinline__ void gemm_body(const unsigned short* __restrict__ A,
                                          const unsigned short* __restrict__ W,
                                          const float* __restrict__ bias,
                                          float* __restrict__ outF,
                                          unsigned short* __restrict__ outB,
                                          int M, int mode, int m0, int n0) {
  constexpr int K = DIM, N = DIM;
  __shared__ unsigned short As[2][128 * 32];
  __shared__ unsigned short Ws[2][128 * 32];
  int tid = threadIdx.x;
  int w = tid >> 6, lane = tid & 63;
  int wr = w >> 1, wc = w & 1, q4 = lane >> 4, ql = lane & 15;

  f32x4 acc[4][4];
  const f32x4 zero4 = {0.f, 0.f, 0.f, 0.f};
#pragma unroll
  for (int i = 0; i < 4; i++)
#pragma unroll
    for (int j = 0; j < 4; j++) acc[i][j] = zero4;

  for (int k0 = 0; k0 < K; k0 += 64) {
    __syncthreads();
#pragma unroll
    for (int half = 0; half < 2; half++) {
#pragma unroll
      for (int r = 0; r < 2; r++) {
        int idx = r * 256 + tid;
        int row = idx >> 2, ch = idx & 3;
        int am = m0 + row; am = (am < M) ? am : (M - 1);
        gl_lds16(A + (size_t)am * K + k0 + half * 32 + ch * 8, &As[half][idx * 8]);
        gl_lds16(W + (size_t)(n0 + row) * K + k0 + half * 32 + ch * 8, &Ws[half][idx * 8]);
      }
    }
    __syncthreads();
#pragma unroll
    for (int half = 0; half < 2; half++) {
      short8 af[4], wf[4];
#pragma unroll
      for (int i = 0; i < 4; i++)
        af[i] = *(const short8*)&As[half][(wr * 64 + i * 16 + ql) * 32 + q4 * 8];
#pragma unroll
      for (int j = 0; j < 4; j++)
        wf[j] = *(const short8*)&Ws[half][(wc * 64 + j * 16 + ql) * 32 + q4 * 8];
#pragma unroll
      for (int i = 0; i < 4; i++)
#pragma unroll
        for (int j = 0; j < 4; j++)
          acc[i][j] = __builtin_amdgcn_mfma_f32_16x16x32_bf16(af[i], wf[j], acc[i][j], 0, 0, 0);
    }
  }

  float bb[4];
#pragma unroll
  for (int j = 0; j < 4; j++) bb[j] = bias[n0 + wc * 64 + j * 16 + ql];
#pragma unroll
  for (int i = 0; i < 4; i++) {
#pragma unroll
    for (int rg = 0; rg < 4; rg++) {
      int row = m0 + wr * 64 + i * 16 + q4 * 4 + rg;
      if (row < M) {
#pragma unroll
        for (int j = 0; j < 4; j++) {
          int col = n0 + wc * 64 + j * 16 + ql;
          float v = acc[i][j][rg] + bb[j];
          if (mode == 0) outF[(size_t)row * N + col] = v;
          else           outB[(size_t)row * N + col] = f2bf(v);
        }
      }
    }
  }
}

// qkv: flat grid 1080 = 8 XCD chunks of 135 (= one z each, W L2-resident).
// All three outputs bf16.
__global__ __launch_bounds__(256, 4) void gemm_qkv_kernel(
    const unsigned short* __restrict__ xb,
    const unsigned short* __restrict__ wqb, const unsigned short* __restrict__ wkb,
    const unsigned short* __restrict__ wvb,
    const float* __restrict__ bq, const float* __restrict__ bk, const float* __restrict__ bv,
    unsigned short* __restrict__ Yqb, unsigned short* __restrict__ Ykb,
    unsigned short* __restrict__ Vb) {
  const int NWG = 3 * 30 * 12;             // 1080
  int bid = blockIdx.x;
  int xcd = bid & 7, bix = bid >> 3;
  int wg = xcd * (NWG >> 3) + bix;         // chunks of 135
  int z = wg / 360;
  int r = wg - z * 360;
  int m = r / 12, n = r % 12;
  const unsigned short* W = (z == 0) ? wqb : ((z == 1) ? wkb : wvb);
  const float* bias       = (z == 0) ? bq  : ((z == 1) ? bk  : bv);
  unsigned short* dst     = (z == 0) ? Yqb : ((z == 1) ? Ykb : Vb);
  gemm_body(xb, W, bias, nullptr, dst, S_TOT, 1, m * 128, n * 128);
}

// out: flat grid 360 = 8 XCD chunks of 45.
__global__ __launch_bounds__(256, 4) void gemm_out_kernel(
    const unsigned short* __restrict__ AO, const unsigned short* __restrict__ wob,
    const float* __restrict__ bo, float* __restrict__ out) {
  const int NWG = 30 * 12;                 // 360
  int bid = blockIdx.x;
  int xcd = bid & 7, bix = bid >> 3;
  int wg = xcd * (NWG >> 3) + bix;         // chunks of 45
  int m = wg / 12, n = wg % 12;
  gemm_body(AO, wob, bo, out, nullptr, S_TOT, 0, m * 128, n * 128);
}

// ---------------------------------------------------------------------------
// RMSNorm + RoPE, bf16 input (Yqb/Ykb). Q pre-scaled by sm_scale*log2(e).
// ---------------------------------------------------------------------------
__global__ __launch_bounds__(256) void normrope_kernel(
    const unsigned short* __restrict__ Yqb, const unsigned short* __restrict__ Ykb,
    const float* __restrict__ gq, const float* __restrict__ gk,
    const float* __restrict__ freqs,
    unsigned short* __restrict__ Qb, unsigned short* __restrict__ Kb) {
  int s = blockIdx.x;
  int tid = threadIdx.x;
  int w = tid >> 6, lane = tid & 63;
  const ushort2* yq2 = (const ushort2*)(Yqb + (size_t)s * DIM);
  const ushort2* yk2 = (const ushort2*)(Ykb + (size_t)s * DIM);
  f32x2 vq[3], vk[3];
  float ssq = 0.f, ssk = 0.f;
#pragma unroll
  for (int r = 0; r < 3; r++) {
    int p = tid + 256 * r;
    ushort2 uq = yq2[p], uk = yk2[p];
    vq[r].x = bf2f(uq.x); vq[r].y = bf2f(uq.y);
    vk[r].x = bf2f(uk.x); vk[r].y = bf2f(uk.y);
    ssq += vq[r].x * vq[r].x + vq[r].y * vq[r].y;
    ssk += vk[r].x * vk[r].x + vk[r].y * vk[r].y;
  }
#pragma unroll
  for (int d = 1; d < 64; d <<= 1) {
    ssq += __shfl_xor(ssq, d);
    ssk += __shfl_xor(ssk, d);
  }
  __shared__ float rq[4], rk[4];
  if (lane == 0) { rq[w] = ssq; rk[w] = ssk; }
  __syncthreads();
  float tq = rq[0] + rq[1] + rq[2] + rq[3];
  float tk = rk[0] + rk[1] + rk[2] + rk[3];
  const float SM_L2 = 0.08838834764831845f * 1.4426950408889634f; // scale*log2e
  float invq = rsqrtf(tq * (1.f / DIM) + 1e-6f) * SM_L2;
  float invk = rsqrtf(tk * (1.f / DIM) + 1e-6f);

  int fi = s / (26 * 48);
  int hi = (s / 48) % 26;
  int wi = s % 48;
#pragma unroll
  for (int r = 0; r < 3; r++) {
    int p = tid + 256 * r;
    int c = p & 63;
    int frow = (c < 22) ? fi : ((c < 43) ? hi : wi);
    float ang = freqs[frow * 64 + c];
    float sn, cs;
    __sincosf(ang, &sn, &cs);
    {
      float a = vq[r].x * invq * gq[2 * p];
      float b = vq[r].y * invq * gq[2 * p + 1];
      ushort2 o; o.x = f2bf(a * cs - b * sn); o.y = f2bf(a * sn + b * cs);
      ((ushort2*)Qb)[(size_t)s * (DIM / 2) + p] = o;
    }
    {
      float a = vk[r].x * invk * gk[2 * p];
      float b = vk[r].y * invk * gk[2 * p + 1];
      ushort2 o; o.x = f2bf(a * cs - b * sn); o.y = f2bf(a * sn + b * cs);
      ((ushort2*)Kb)[(size_t)s * (DIM / 2) + p] = o;
    }
  }
}

// ---------------------------------------------------------------------------
// V transpose (unchanged, proven)
// ---------------------------------------------------------------------------
__global__ __launch_bounds__(256) void vtrans_kernel(const unsigned short* __restrict__ Vb,
                                                     unsigned short* __restrict__ Vt) {
  int d0 = blockIdx.x * 64, s0 = blockIdx.y * 64;
  __shared__ unsigned short t[64][65];
  int tid = threadIdx.x;
#pragma unroll
  for (int r = 0; r < 4; r++) {
    int idx = r * 256 + tid;
    int sr = idx >> 4, c4 = (idx & 15) * 4;
    ushort4 v; v.x = v.y = v.z = v.w = 0;
    int s = s0 + sr;
    if (s < S_TOT) v = *(const ushort4*)(Vb + (size_t)s * DIM + d0 + c4);
    t[sr][c4 + 0] = v.x; t[sr][c4 + 1] = v.y; t[sr][c4 + 2] = v.z; t[sr][c4 + 3] = v.w;
  }
  __syncthreads();
#pragma unroll
  for (int r = 0; r < 4; r++) {
    int idx = r * 256 + tid;
    int dr = idx >> 4, s4 = (idx & 15) * 4;
    if (s0 + s4 < S_TOT) {
      ushort4 v;
      v.x = t[s4 + 0][dr]; v.y = t[s4 + 1][dr]; v.z = t[s4 + 2][dr]; v.w = t[s4 + 3][dr];
      *(ushort4*)(Vt + (size_t)(d0 + dr) * S_TOT + s0 + s4) = v;
    }
  }
}

// ---------------------------------------------------------------------------
// Flash attention (R11 verbatim): 32x32x16 MFMA, in-register P,
// 4 waves x 32q = 128q/block, double-buffered K/V (KVBLK=64) with counted
// vmcnt(8), split-K=2, grid 720 (XCD chunks of 90 — verified FETCH 23MB,
// 151.7us). Emits unnormalized O f32 + (m,l); reduce combines.
// ---------------------------------------------------------------------------
__global__ __launch_bounds__(256, 2) void attn_kernel(
    const unsigned short* __restrict__ Qb, const unsigned short* __restrict__ Kb,
    const unsigned short* __restrict__ Vt,
    float* __restrict__ Opart, float2* __restrict__ Ml,
    const int* __restrict__ seq_lens) {
  const int NWG = QT2 * NHEAD * KSPLIT;    // 720
  int bid = blockIdx.x;
  int xcd = bid & 7, bix = bid >> 3;
  const int qc = NWG >> 3;                 // 90
  int wg = xcd * qc + bix;
  int qt  = wg % QT2;
  int rem = wg / QT2;                      // 0..23, consecutive share (h,split)
  int h    = rem >> 1;
  int sidx = rem & 1;
  int tbeg = sidx ? 30 : 0;
  int tend = sidx ? KVT : 30;

  int tid = threadIdx.x;                   // 0..255
  int wv = tid >> 6, lane = tid & 63;
  int lo = lane & 31, hf = lane >> 5;
  int seqlen = seq_lens[0]; if (seqlen > S_TOT) seqlen = S_TOT;

  __shared__ unsigned short Kl[2][64 * 128];  // 2 x 16 KB, chunk-swizzled
  __shared__ unsigned short Vl[2][128 * 64];  // 2 x 16 KB, chunk-swizzled

  int q0 = qt * 128 + wv * 32;
  bool wact = (q0 < S_TOT);
  const size_t hoff = (size_t)h * HD;

  auto stage = [&](int buf, int t) {
    int k0 = t * 64;
    const unsigned short* kseg = Kb + (size_t)k0 * DIM + hoff;
#pragma unroll
    for (int r = 0; r < 4; r++) {
      int idx = r * 256 + tid;
      int row = idx >> 4, c = idx & 15;
      int g = c ^ (row & 15);
      gl_lds16(kseg + (size_t)row * DIM + g * 8, &Kl[buf][idx * 8]);
    }
    int kmax = S_TOT - 8 - k0;             // clamp key-chunk start (last tile)
#pragma unroll
    for (int r = 0; r < 4; r++) {
      int idx = r * 256 + tid;
      int row = idx >> 3, c = idx & 7;
      int g = c ^ (row & 7);
      int kc = g * 8; if (kc > kmax) kc = kmax;
      gl_lds16(Vt + (hoff + row) * S_TOT + k0 + kc, &Vl[buf][idx * 8]);
    }
  };

  // Q B-frags (hoisted): qf[ks] = Q[q0+lo][ks*16 + hf*8 .. +7]
  short8 qf[8];
  {
    int qrow = q0 + lo; if (qrow > S_TOT - 1) qrow = S_TOT - 1;
#pragma unroll
    for (int ks = 0; ks < 8; ks++)
      qf[ks] = *(const short8*)(Qb + (size_t)qrow * DIM + hoff + ks * 16 + hf * 8);
  }
  asm volatile("s_waitcnt vmcnt(0)" ::: "memory");  // Q landed; vmcnt clean

  f32x16 o[4];
#pragma unroll
  for (int dq = 0; dq < 4; dq++)
#pragma unroll
    for (int r = 0; r < 16; r++) o[dq][r] = 0.f;
  float m_run = -3.0e38f, l_run = 0.f;

  stage(0, tbeg);                          // prologue: first tile in flight

  for (int t = tbeg; t < tend; ++t) {
    int cur = (t - tbeg) & 1;
    int k0 = t * 64;
    __builtin_amdgcn_s_barrier();          // all reads of buf[cur^1] done
    asm volatile("" ::: "memory");
    if (t + 1 < tend) {
      stage(cur ^ 1, t + 1);               // prefetch next tile (8 gl_lds/thr)
      asm volatile("s_waitcnt vmcnt(8)" ::: "memory");   // tile t landed (mine)
    } else {
      asm volatile("s_waitcnt vmcnt(0)" ::: "memory");
    }
    __builtin_amdgcn_sched_barrier(0);
    __builtin_amdgcn_s_barrier();          // tile t landed (everyone)
    asm volatile("" ::: "memory");
    if (!wact) continue;

    // ---- QK^T: two 32-key halves, dual accumulation chains ----
    f32x16 s0, s1;
#pragma unroll
    for (int r = 0; r < 16; r++) { s0[r] = 0.f; s1[r] = 0.f; }
    __builtin_amdgcn_s_setprio(1);
#pragma unroll
    for (int ks = 0; ks < 8; ks++) {
      int sl = ((ks * 2 + hf) ^ (lo & 15)) * 8;
      short8 kf0 = *(const short8*)&Kl[cur][lo * 128 + sl];
      short8 kf1 = *(const short8*)&Kl[cur][(32 + lo) * 128 + sl];
      s0 = __builtin_amdgcn_mfma_f32_32x32x16_bf16(kf0, qf[ks], s0, 0, 0, 0);
      s1 = __builtin_amdgcn_mfma_f32_32x32x16_bf16(kf1, qf[ks], s1, 0, 0, 0);
    }
    __builtin_amdgcn_s_setprio(0);

    // ---- mask (ragged last tile only) ----
    if (k0 + 64 > seqlen) {
#pragma unroll
      for (int r = 0; r < 16; r++) {
        int key0 = k0 + (r & 3) + 8 * (r >> 2) + 4 * hf;
        if (key0      >= seqlen) s0[r] = -3.0e38f;
        if (key0 + 32 >= seqlen) s1[r] = -3.0e38f;
      }
    }

    // ---- online softmax (exp2 domain; Q pre-scaled) ----
    float mloc = s0[0];
#pragma unroll
    for (int r = 1; r < 16; r++) mloc = fmaxf(mloc, s0[r]);
#pragma unroll
    for (int r = 0; r < 16; r++) mloc = fmaxf(mloc, s1[r]);
    mloc = fmaxf(mloc, __shfl_xor(mloc, 32));

    // defer-max (T13): rescale only when growth > 8 (rare); alpha needs a
    // lane->reg-row redistribution (q=lane&31 -> q=(r&3)+8*(r>>2)+4*hf)
    if (!__all(mloc <= m_run + 8.0f)) {
      float mnew = fmaxf(m_run, mloc);
      float alpha = exp2f(m_run - mnew);   // 0 on first tile
      m_run = mnew;
      l_run *= alpha;
      int lb = lane & 32;
      float ar[16];
#pragma unroll
      for (int r = 0; r < 16; r++)
        ar[r] = __shfl(alpha, ((r & 3) + 8 * (r >> 2) + 4 * hf) | lb);
#pragma unroll
      for (int dq = 0; dq < 4; dq++)
#pragma unroll
        for (int r = 0; r < 16; r++) o[dq][r] *= ar[r];
    }

    // ---- P = exp2(s - m) -> bf16 A-frags fully in-register (T12) ----
    float lloc = 0.f;
    short8 pa[4];
    {
      float p[16];
#pragma unroll
      for (int r = 0; r < 16; r++) { p[r] = exp2f(s0[r] - m_run); lloc += p[r]; }
      unsigned pr[8];
#pragma unroll
      for (int i = 0; i < 8; i++)
        asm("v_cvt_pk_bf16_f32 %0, %1, %2" : "=v"(pr[i]) : "v"(p[2 * i]), "v"(p[2 * i + 1]));
      asm volatile("v_permlane32_swap_b32 %0, %1" : "+v"(pr[0]), "+v"(pr[2]));
      asm volatile("v_permlane32_swap_b32 %0, %1" : "+v"(pr[1]), "+v"(pr[3]));
      asm volatile("v_permlane32_swap_b32 %0, %1" : "+v"(pr[4]), "+v"(pr[6]));
      asm volatile("v_permlane32_swap_b32 %0, %1" : "+v"(pr[5]), "+v"(pr[7]));
      pa[0] = mk8(pr[0], pr[1], pr[2], pr[3]);
      pa[1] = mk8(pr[4], pr[5], pr[6], pr[7]);
    }
    {
      float p[16];
#pragma unroll
      for (int r = 0; r < 16; r++) { p[r] = exp2f(s1[r] - m_run); lloc += p[r]; }
      unsigned pr[8];
#pragma unroll
      for (int i = 0; i < 8; i++)
        asm("v_cvt_pk_bf16_f32 %0, %1, %2" : "=v"(pr[i]) : "v"(p[2 * i]), "v"(p[2 * i + 1]));
      asm volatile("v_permlane32_swap_b32 %0, %1" : "+v"(pr[0]), "+v"(pr[2]));
      asm volatile("v_permlane32_swap_b32 %0, %1" : "+v"(pr[1]), "+v"(pr[3]));
      asm volatile("v_permlane32_swap_b32 %0, %1" : "+v"(pr[4]), "+v"(pr[6]));
      asm volatile("v_permlane32_swap_b32 %0, %1" : "+v"(pr[5]), "+v"(pr[7]));
      pa[2] = mk8(pr[0], pr[1], pr[2], pr[3]);
      pa[3] = mk8(pr[4], pr[5], pr[6], pr[7]);
    }
    lloc += __shfl_xor(lloc, 32);
    l_run += lloc;

    // ---- PV: O[q][d] += P.V, 4 independent acc chains ----
    __builtin_amdgcn_s_setprio(1);
#pragma unroll
    for (int kh2 = 0; kh2 < 4; kh2++) {
      int sl = ((kh2 * 2 + hf) ^ (lo & 7)) * 8;
#pragma unroll
      for (int dq = 0; dq < 4; dq++) {
        short8 vb = *(const short8*)&Vl[cur][(dq * 32 + lo) * 64 + sl];
        o[dq] = __builtin_amdgcn_mfma_f32_32x32x16_bf16(pa[kh2], vb, o[dq], 0, 0, 0);
      }
    }
    __builtin_amdgcn_s_setprio(0);
  }

  if (wact) {
    // unnormalized partials: O f32 [128 q][128 d] + (m,l) per q-row
    size_t ob = (((size_t)sidx * NHEAD + h) * QT2 + qt) * (128 * 128);
#pragma unroll
    for (int dq = 0; dq < 4; dq++)
#pragma unroll
      for (int r = 0; r < 16; r++) {
        int row = wv * 32 + (r & 3) + 8 * (r >> 2) + 4 * hf;
        Opart[ob + (size_t)row * 128 + dq * 32 + lo] = o[dq][r];
      }
    if (lane < 32) {
      float2 ml; ml.x = m_run; ml.y = l_run;
      Ml[((size_t)(sidx * NHEAD + h) * QT2 + qt) * 128 + wv * 32 + lo] = ml;
    }
  }
}

// ---------------------------------------------------------------------------
// split-K reduce, float4-vectorized: each thread combines 4 d-elements.
// AO = (w0*O0 + w1*O1) / (w0*l0 + w1*l1), w_s = exp2(m_s - max m).
// Grid: NHEAD*S_TOT*(HD/4) / 256 = 5616.
// ---------------------------------------------------------------------------
__global__ __launch_bounds__(256) void reduce_kernel(
    const float* __restrict__ Opart, const float2* __restrict__ Ml,
    unsigned short* __restrict__ AO) {
  int flat = blockIdx.x * 256 + threadIdx.x;
  int d4 = (flat & 31) * 4;                // 32 groups of 4 per row
  int r = flat >> 5;                       // 0 .. NHEAD*S_TOT-1
  int h = r / S_TOT;
  int q = r - h * S_TOT;
  int qt = q >> 7, qi = q & 127;
  size_t ob = (((size_t)h * QT2) + qt) * (128 * 128) + (size_t)qi * 128 + d4;
  const size_t so = (size_t)NHEAD * QT2 * 128 * 128;
  int mb = (h * QT2 + qt) * 128 + qi;
  const int sm = NHEAD * QT2 * 128;
  float2 ml0 = Ml[mb], ml1 = Ml[mb + sm];
  float mm = fmaxf(ml0.x, ml1.x);
  float w0 = exp2f(ml0.x - mm), w1 = exp2f(ml1.x - mm);
  float il = 1.0f / (w0 * ml0.y + w1 * ml1.y);
  float4 a = *(const float4*)(Opart + ob);
  float4 b = *(const float4*)(Opart + ob + so);
  ushort4 o;
  o.x = f2bf((w0 * a.x + w1 * b.x) * il);
  o.y = f2bf((w0 * a.y + w1 * b.y) * il);
  o.z = f2bf((w0 * a.z + w1 * b.z) * il);
  o.w = f2bf((w0 * a.w + w1 * b.w) * il);
  *(ushort4*)(AO + (size_t)q * DIM + h * HD + d4) = o;
}

// ---------------------------------------------------------------------------
extern "C" void kernel_launch(void* const* d_in, const int* in_sizes, int n_in,
                              void* d_out, int out_size, void* d_ws, size_t ws_size,
                              hipStream_t stream) {
  const float* x    = (const float*)d_in[0];
  const float* wq   = (const float*)d_in[1];
  const float* bq   = (const float*)d_in[2];
  const float* wk   = (const float*)d_in[3];
  const float* bk   = (const float*)d_in[4];
  const float* wv   = (const float*)d_in[5];
  const float* bv   = (const float*)d_in[6];
  const float* wo   = (const float*)d_in[7];
  const float* bo   = (const float*)d_in[8];
  const float* gq   = (const float*)d_in[9];
  const float* gk   = (const float*)d_in[10];
  const float* freqs = (const float*)d_in[11];
  const int*   seq  = (const int*)d_in[12];

  char* ws = (char*)d_ws;
  const size_t SZ_X = (size_t)S_TOT * DIM * 2;   // bf16 [S,DIM]  = 11.50 MB
  const size_t SZ_W = (size_t)DIM * DIM * 2;     // bf16 [DIM,DIM] = 4.72 MB

  // Layout: xb,Yqb,Ykb,wqb,wkb,wvb (48.66MB, ALL dead after normrope) laid
  // contiguous at base -> overlaid by Opart 47.19MB + Ml 0.74MB for attn.
  size_t off = 0;
  unsigned short* xb  = (unsigned short*)(ws + off); off += SZ_X;
  unsigned short* Yqb = (unsigned short*)(ws + off); off += SZ_X;
  unsigned short* Ykb = (unsigned short*)(ws + off); off += SZ_X;
  unsigned short* wqb = (unsigned short*)(ws + off); off += SZ_W;
  unsigned short* wkb = (unsigned short*)(ws + off); off += SZ_W;
  unsigned short* wvb = (unsigned short*)(ws + off); off += SZ_W;
  unsigned short* wob = (unsigned short*)(ws + off); off += SZ_W;
  unsigned short* Vb  = (unsigned short*)(ws + off); off += SZ_X;
  unsigned short* Qb  = (unsigned short*)(ws + off); off += SZ_X;
  unsigned short* Kb  = (unsigned short*)(ws + off); off += SZ_X;
  unsigned short* Vt  = (unsigned short*)(ws + off); off += SZ_X;
  unsigned short* AO  = (unsigned short*)(ws + off); off += SZ_X;

  float*  Opart = (float*)ws;            // 2*12*30*128*128*4 = 47.19 MB
  float2* Ml    = (float2*)(ws + (size_t)KSPLIT * NHEAD * QT2 * 128 * 128 * 4);

  int total4 = NX4 + 4 * NW4;
  cvt5_kernel<<<dim3((total4 + 255) / 256), 256, 0, stream>>>(
      x, wq, wk, wv, wo, xb, wqb, wkb, wvb, wob);

  gemm_qkv_kernel<<<dim3(3 * 30 * 12), 256, 0, stream>>>(
      xb, wqb, wkb, wvb, bq, bk, bv, Yqb, Ykb, Vb);

  normrope_kernel<<<dim3(S_TOT), 256, 0, stream>>>(Yqb, Ykb, gq, gk, freqs, Qb, Kb);

  vtrans_kernel<<<dim3(DIM / 64, (S_TOT + 63) / 64), 256, 0, stream>>>(Vb, Vt);

  attn_kernel<<<dim3(QT2 * NHEAD * KSPLIT), 256, 0, stream>>>(
      Qb, Kb, Vt, Opart, Ml, seq);

  reduce_kernel<<<dim3(NHEAD * S_TOT * (HD / 4) / 256), 256, 0, stream>>>(
      Opart, Ml, AO);

  gemm_out_kernel<<<dim3(30 * 12), 256, 0, stream>>>(AO, wob, bo, (float*)d_out);
}